// Round 8
// baseline (726.840 us; speedup 1.0000x reference)
//
#include <hip/hip_runtime.h>
#include <hip/hip_bf16.h>
#include <math.h>

#define DM 1024   // d_model
#define DI 2048   // d_inner
#define DS 16     // d_state
#define DC 4      // d_conv
#define DR 64     // dt_rank
#define NB 4      // batch
#define SL 2048   // seqlen
#define BL (NB * SL)        // 8192 rows
#define DXP (DR + 2 * DS)   // 96
#define NC 32               // scan chunks
#define CL (SL / NC)        // 64 steps per chunk

typedef __hip_bfloat16 bf16;
typedef __attribute__((ext_vector_type(8))) short short8;
typedef __attribute__((ext_vector_type(4))) float floatx4;
typedef unsigned int u32;

__device__ __forceinline__ float to_f(float v) { return v; }
__device__ __forceinline__ float to_f(bf16 v) { return __bfloat162float(v); }
template <typename T> __device__ __forceinline__ T from_f(float v);
template <> __device__ __forceinline__ float from_f<float>(float v) { return v; }
template <> __device__ __forceinline__ bf16 from_f<bf16>(float v) { return __float2bfloat16(v); }

// async 16B/lane global -> LDS DMA (dest = wave-uniform base + lane*16)
__device__ __forceinline__ void cp16(const ushort* g, const ushort* l) {
  __builtin_amdgcn_global_load_lds((const __attribute__((address_space(1))) u32*)g,
                                   (__attribute__((address_space(3))) u32*)l, 16, 0, 0);
}

// ---------------- fp32 -> bf16 conversion ----------------
__global__ __launch_bounds__(256) void f2b_k(const float* __restrict__ src,
                                             bf16* __restrict__ dst, int n) {
  int i = blockIdx.x * 256 + threadIdx.x;
  if (i < n) dst[i] = from_f<bf16>(src[i]);
}

// ---------------- RMSNorm (bf16 out) ----------------
__global__ __launch_bounds__(256) void rmsnorm_k(const float* __restrict__ x,
                                                 const float* __restrict__ w,
                                                 bf16* __restrict__ o) {
  int row = blockIdx.x;
  const float* xr = x + (size_t)row * DM;
  float ss = 0.f;
  for (int i = threadIdx.x; i < DM; i += 256) { float v = xr[i]; ss += v * v; }
  for (int off = 32; off > 0; off >>= 1) ss += __shfl_down(ss, off);
  __shared__ float sred[4];
  __shared__ float sscale;
  if ((threadIdx.x & 63) == 0) sred[threadIdx.x >> 6] = ss;
  __syncthreads();
  if (threadIdx.x == 0) {
    float t = sred[0] + sred[1] + sred[2] + sred[3];
    sscale = rsqrtf(t / (float)DM + 1.1920929e-7f);
  }
  __syncthreads();
  float sc = sscale;
  bf16* orow = o + (size_t)row * DM;
  for (int i = threadIdx.x; i < DM; i += 256) orow[i] = from_f<bf16>(xr[i] * sc * w[i]);
}

// ======== MFMA bf16 GEMM, async global_load_lds staging, 128x128 tile ========
// MODE 1: in_proj  -> n<nsplit: raw bf16 to Cx ; n>=nsplit: silu -> Cz
// MODE 2: out_proj -> fp32 Cf = acc + R (residual)
// MODE 3: dt_proj  -> bf16 Cx = softplus(acc + bias[n])
#define TM 128
#define TN 128
#define TK 32
template <int MODE>
__global__ __launch_bounds__(256) void gemm_mfma(const bf16* __restrict__ A,
                                                 const bf16* __restrict__ W,
                                                 int M, int N, int K,
                                                 bf16* __restrict__ Cx,
                                                 bf16* __restrict__ Cz, int nsplit,
                                                 float* __restrict__ Cf,
                                                 const float* __restrict__ R,
                                                 const float* __restrict__ bias) {
  __shared__ ushort Asm[TM][TK];   // 8 KiB, UNPADDED (global_load_lds layout)
  __shared__ ushort Bsm[TN][TK];   // 8 KiB
  int bm = blockIdx.y * TM, bn = blockIdx.x * TN;
  int tid = threadIdx.x;
  int lane = tid & 63, wave = tid >> 6;
  int wm = (wave & 1) * 64, wn = (wave >> 1) * 64;
  int row15 = lane & 15, quad = lane >> 4;

  // staging: each wave issues 2 A + 2 B async 1 KiB DMAs (16 rows each)
  int jr = wave * 32 + (lane >> 2) * 2;      // covers rows wave*32 .. wave*32+31 (pairs)
  int arow0 = wave * 32;                     // first row of this wave's A/B slab
  int kch = (lane & 3) * 8;                  // 8-ushort chunk within the 32-wide row

  floatx4 acc[4][4] = {};

  const ushort* Au = (const ushort*)A;
  const ushort* Wu = (const ushort*)W;
  for (int k0 = 0; k0 < K; k0 += TK) {
    const ushort* ga0 = Au + (size_t)(bm + arow0 + (lane >> 2)) * K + k0 + kch;
    const ushort* ga1 = Au + (size_t)(bm + arow0 + 16 + (lane >> 2)) * K + k0 + kch;
    const ushort* gb0 = Wu + (size_t)(bn + arow0 + (lane >> 2)) * K + k0 + kch;
    const ushort* gb1 = Wu + (size_t)(bn + arow0 + 16 + (lane >> 2)) * K + k0 + kch;
    cp16(ga0, &Asm[arow0][0]);
    cp16(ga1, &Asm[arow0 + 16][0]);
    cp16(gb0, &Bsm[arow0][0]);
    cp16(gb1, &Bsm[arow0 + 16][0]);
    __syncthreads();   // drains vmcnt(0): DMA complete, LDS visible
    short8 a_f[4], b_f[4];
#pragma unroll
    for (int i = 0; i < 4; ++i)
      a_f[i] = *(const short8*)&Asm[wm + i * 16 + row15][quad * 8];
#pragma unroll
    for (int j = 0; j < 4; ++j)
      b_f[j] = *(const short8*)&Bsm[wn + j * 16 + row15][quad * 8];
#pragma unroll
    for (int i = 0; i < 4; ++i)
#pragma unroll
      for (int j = 0; j < 4; ++j)
        acc[i][j] = __builtin_amdgcn_mfma_f32_16x16x32_bf16(a_f[i], b_f[j], acc[i][j], 0, 0, 0);
    __syncthreads();   // all reads done before next iter's DMA overwrites
  }
#pragma unroll
  for (int mi = 0; mi < 4; ++mi) {
#pragma unroll
    for (int ni = 0; ni < 4; ++ni) {
#pragma unroll
      for (int reg = 0; reg < 4; ++reg) {
        int grow = bm + wm + mi * 16 + quad * 4 + reg;
        int gcol = bn + wn + ni * 16 + row15;
        float v = acc[mi][ni][reg];
        if (MODE == 1) {
          if (gcol < nsplit) {
            Cx[(size_t)grow * DI + gcol] = from_f<bf16>(v);
          } else {
            float g = v / (1.f + __expf(-v));
            Cz[(size_t)grow * DI + (gcol - nsplit)] = from_f<bf16>(g);
          }
        } else if (MODE == 2) {
          size_t o = (size_t)grow * N + gcol;
          Cf[o] = v + R[o];
        } else {  // MODE 3: dt softplus
          float t = v + bias[gcol];
          float sp = (t > 20.f) ? t : log1pf(__expf(t));
          Cx[(size_t)grow * N + gcol] = from_f<bf16>(sp);
        }
      }
    }
  }
  (void)jr;
}

// ======== x_proj split-K MFMA: xdbl[BL,96] += u[BL,2048-slice] @ xpw^T ========
#define XKS 128
#define LDK 40
__global__ __launch_bounds__(256) void xproj_k(const bf16* __restrict__ u,
                                               const bf16* __restrict__ w,
                                               float* __restrict__ xdbl) {
  __shared__ ushort Asm[128][LDK];
  __shared__ ushort Bsm[96][LDK];
  int kbase = blockIdx.x * XKS;
  int bm = blockIdx.y * 128;
  int tid = threadIdx.x;
  int lane = tid & 63, wave = tid >> 6;
  int row15 = lane & 15, quad = lane >> 4;
  int srow = tid >> 1, skoff = (tid & 1) * 16;

  floatx4 acc[2][6] = {};
  const ushort* Au = (const ushort*)u;
  const ushort* Wu = (const ushort*)w;
  for (int k0 = kbase; k0 < kbase + XKS; k0 += TK) {
    const ushort* ag = Au + (size_t)(bm + srow) * DI + k0 + skoff;
    *(short8*)&Asm[srow][skoff]     = *(const short8*)ag;
    *(short8*)&Asm[srow][skoff + 8] = *(const short8*)(ag + 8);
    if (tid < 192) {
      const ushort* wg = Wu + (size_t)srow * DI + k0 + skoff;
      *(short8*)&Bsm[srow][skoff]     = *(const short8*)wg;
      *(short8*)&Bsm[srow][skoff + 8] = *(const short8*)(wg + 8);
    }
    __syncthreads();
    short8 a_f[2], b_f[6];
#pragma unroll
    for (int i = 0; i < 2; ++i)
      a_f[i] = *(const short8*)&Asm[wave * 32 + i * 16 + row15][quad * 8];
#pragma unroll
    for (int j = 0; j < 6; ++j)
      b_f[j] = *(const short8*)&Bsm[j * 16 + row15][quad * 8];
#pragma unroll
    for (int i = 0; i < 2; ++i)
#pragma unroll
      for (int j = 0; j < 6; ++j)
        acc[i][j] = __builtin_amdgcn_mfma_f32_16x16x32_bf16(a_f[i], b_f[j], acc[i][j], 0, 0, 0);
    __syncthreads();
  }
#pragma unroll
  for (int mi = 0; mi < 2; ++mi)
#pragma unroll
    for (int nj = 0; nj < 6; ++nj)
#pragma unroll
      for (int reg = 0; reg < 4; ++reg) {
        int grow = bm + wave * 32 + mi * 16 + quad * 4 + reg;
        int gcol = nj * 16 + row15;
        atomicAdd(&xdbl[(size_t)grow * DXP + gcol], acc[mi][nj][reg]);
      }
}

// ---- extract xdbl[:, 0:64] -> bf16 [BL, 64] for the dt MFMA ----
__global__ __launch_bounds__(256) void dtex_k(const float* __restrict__ xdbl,
                                              bf16* __restrict__ dtin) {
  int i = blockIdx.x * 256 + threadIdx.x;  // BL*DR
  int r = i >> 6, c = i & 63;
  dtin[i] = from_f<bf16>(xdbl[(size_t)r * DXP + c]);
}

// ---------------- causal depthwise conv (K=4) + SiLU ----------------
__global__ __launch_bounds__(256) void conv_silu_k(const bf16* __restrict__ xin,
                                                   const float* __restrict__ cw,
                                                   const float* __restrict__ cb,
                                                   bf16* __restrict__ u) {
  int idx = blockIdx.x * 256 + threadIdx.x;
  if (idx >= BL * DI) return;
  int c = idx & (DI - 1);
  int bl = idx / DI;
  int l = bl & (SL - 1);
  float acc = cb[c];
#pragma unroll
  for (int k = 0; k < DC; ++k) {
    int lk = l - (DC - 1) + k;
    if (lk >= 0) acc += to_f(xin[((size_t)(bl - l + lk)) * DI + c]) * cw[c * DC + k];
  }
  u[idx] = from_f<bf16>(acc / (1.f + __expf(-acc)));
}

// ======== chunked selective scan ========
__global__ __launch_bounds__(256) void scan_p1(const bf16* __restrict__ dts,
                                               const bf16* __restrict__ u,
                                               const float* __restrict__ xdbl,
                                               const float* __restrict__ A_log,
                                               float* __restrict__ Pbuf,
                                               float* __restrict__ Qbuf) {
  int bid = blockIdx.x;
  int b = bid >> 8;
  int c = (bid >> 3) & (NC - 1);
  int d = (bid & 7) * 256 + threadIdx.x;

  float A[DS], h[DS], P[DS];
#pragma unroll
  for (int s = 0; s < DS; ++s) {
    A[s] = -__expf(A_log[d * DS + s]);
    h[s] = 0.f; P[s] = 1.f;
  }
  size_t bl0 = (size_t)b * SL + c * CL;
  size_t base = bl0 * DI + d;
  size_t xb = bl0 * DXP + DR;
  for (int l = 0; l < CL; ++l) {
    float dtv = to_f(dts[base]);
    float uv = to_f(u[base]);
    float du = dtv * uv;
#pragma unroll
    for (int s = 0; s < DS; ++s) {
      float Bv = xdbl[xb + s];
      float dA = __expf(dtv * A[s]);
      h[s] = dA * h[s] + du * Bv;
      P[s] *= dA;
    }
    base += DI;
    xb += DXP;
  }
  size_t o = ((size_t)(b * NC + c) * DS) * DI + d;
#pragma unroll
  for (int s = 0; s < DS; ++s) {
    Pbuf[o + (size_t)s * DI] = P[s];
    Qbuf[o + (size_t)s * DI] = h[s];
  }
}

__global__ __launch_bounds__(256) void scan_p2(float* __restrict__ Pbuf,
                                               float* __restrict__ Qbuf) {
  int bid = blockIdx.x;
  int b = bid >> 7;
  int s = (bid >> 3) & (DS - 1);
  int d = (bid & 7) * 256 + threadIdx.x;
  float h = 0.f;
  for (int c = 0; c < NC; ++c) {
    size_t idx = ((size_t)((b * NC + c) * DS + s)) * DI + d;
    float Pv = Pbuf[idx];
    float qv = Qbuf[idx];
    Qbuf[idx] = h;
    h = Pv * h + qv;
  }
}

__global__ __launch_bounds__(256) void scan_p3(const bf16* __restrict__ dts,
                                               bf16* __restrict__ u,
                                               const float* __restrict__ xdbl,
                                               const float* __restrict__ A_log,
                                               const float* __restrict__ Dp,
                                               const bf16* __restrict__ g,
                                               const float* __restrict__ Qbuf) {
  int bid = blockIdx.x;
  int b = bid >> 8;
  int c = (bid >> 3) & (NC - 1);
  int d = (bid & 7) * 256 + threadIdx.x;

  float A[DS], h[DS];
  size_t o = ((size_t)(b * NC + c) * DS) * DI + d;
#pragma unroll
  for (int s = 0; s < DS; ++s) {
    A[s] = -__expf(A_log[d * DS + s]);
    h[s] = Qbuf[o + (size_t)s * DI];
  }
  float Dd = Dp[d];
  size_t bl0 = (size_t)b * SL + c * CL;
  size_t base = bl0 * DI + d;
  size_t xb = bl0 * DXP + DR;
  for (int l = 0; l < CL; ++l) {
    float dtv = to_f(dts[base]);
    float uv = to_f(u[base]);
    float gv = to_f(g[base]);
    float du = dtv * uv;
    float p0 = 0.f, p1 = 0.f, p2 = 0.f, p3 = 0.f;
#pragma unroll
    for (int s = 0; s < DS; s += 4) {
      float dA0 = __expf(dtv * A[s + 0]);
      float dA1 = __expf(dtv * A[s + 1]);
      float dA2 = __expf(dtv * A[s + 2]);
      float dA3 = __expf(dtv * A[s + 3]);
      h[s + 0] = dA0 * h[s + 0] + du * xdbl[xb + s + 0];
      h[s + 1] = dA1 * h[s + 1] + du * xdbl[xb + s + 1];
      h[s + 2] = dA2 * h[s + 2] + du * xdbl[xb + s + 2];
      h[s + 3] = dA3 * h[s + 3] + du * xdbl[xb + s + 3];
      p0 += h[s + 0] * xdbl[xb + DS + s + 0];
      p1 += h[s + 1] * xdbl[xb + DS + s + 1];
      p2 += h[s + 2] * xdbl[xb + DS + s + 2];
      p3 += h[s + 3] * xdbl[xb + DS + s + 3];
    }
    float yv = ((p0 + p1) + (p2 + p3)) + Dd * uv;
    u[base] = from_f<bf16>(yv * gv);
    base += DI;
    xb += DXP;
  }
}

extern "C" void kernel_launch(void* const* d_in, const int* in_sizes, int n_in,
                              void* d_out, int out_size, void* d_ws, size_t ws_size,
                              hipStream_t stream) {
  const float* x        = (const float*)d_in[0];
  const float* norm_w   = (const float*)d_in[1];
  const float* in_projw = (const float*)d_in[2];
  const float* conv_w   = (const float*)d_in[3];
  const float* conv_b   = (const float*)d_in[4];
  const float* x_projw  = (const float*)d_in[5];
  const float* dt_projw = (const float*)d_in[6];
  const float* dt_projb = (const float*)d_in[7];
  const float* A_log    = (const float*)d_in[8];
  const float* Dp       = (const float*)d_in[9];
  const float* out_projw= (const float*)d_in[10];
  float* out = (float*)d_out;

  // ---- workspace (~104 MiB), lifetime overlays ----
  char* wsb = (char*)d_ws;
  bf16* x_buf  = (bf16*)wsb;                           // x half; later dt; later opw_bf
  bf16* z_buf  = (bf16*)(wsb + (size_t)BL * DI * 2);   // silu(z) gate
  bf16* u_buf  = (bf16*)(wsb + (size_t)BL * DI * 4);   // xnorm_bf (early) then u/y
  char* ovl    = wsb + (size_t)BL * DI * 6;            // 8 MiB overlay
  bf16* ipw_bf = (bf16*)ovl;                           // phase A: in_proj w bf16 (8 MiB)
  // phase B overlay (after in_proj):
  float* xdbl   = (float*)ovl;                                 // 3 MiB
  bf16*  xpw_bf = (bf16*)(ovl + 3145728);                      // 0.375 MiB
  bf16*  dtw_bf = (bf16*)(ovl + 3538944);                      // 0.25 MiB
  bf16*  dtin_bf= (bf16*)(ovl + 3801088);                      // 1 MiB
  bf16* xnorm_bf = u_buf;
  bf16* dt_buf   = x_buf;   // x half dead after conv
  bf16* opw_bf   = x_buf;   // dt dead after scan p3
  float* Pbuf = out;        // d_out scratch until out_proj
  float* Qbuf = out + (size_t)NB * NC * DS * DI;

  // 1. in_proj weights -> bf16
  f2b_k<<<(2 * DI * DM) / 256, 256, 0, stream>>>(in_projw, ipw_bf, 2 * DI * DM);
  // 2. RMSNorm -> bf16
  rmsnorm_k<<<BL, 256, 0, stream>>>(x, norm_w, xnorm_bf);
  // 3. in_proj (MFMA, async staging): x half -> x_buf ; z half silu -> z_buf
  gemm_mfma<1><<<dim3(2 * DI / TN, BL / TM), 256, 0, stream>>>(
      xnorm_bf, ipw_bf, BL, 2 * DI, DM, x_buf, z_buf, DI, nullptr, nullptr, nullptr);
  // 4. causal conv + silu -> u_buf
  conv_silu_k<<<(BL * DI) / 256, 256, 0, stream>>>(x_buf, conv_w, conv_b, u_buf);
  // 5. x_proj: zero xdbl, convert weights, split-K MFMA with atomic accumulate
  hipMemsetAsync(xdbl, 0, (size_t)BL * DXP * sizeof(float), stream);
  f2b_k<<<(DXP * DI + 255) / 256, 256, 0, stream>>>(x_projw, xpw_bf, DXP * DI);
  f2b_k<<<(DI * DR) / 256, 256, 0, stream>>>(dt_projw, dtw_bf, DI * DR);
  xproj_k<<<dim3(DI / XKS, BL / 128), 256, 0, stream>>>(u_buf, xpw_bf, xdbl);
  // 6. dt input slice -> bf16, dt_proj (MFMA, fused bias+softplus) -> dt_buf
  dtex_k<<<(BL * DR) / 256, 256, 0, stream>>>(xdbl, dtin_bf);
  gemm_mfma<3><<<dim3(DI / TN, BL / TM), 256, 0, stream>>>(
      dtin_bf, dtw_bf, BL, DI, DR, dt_buf, nullptr, 0, nullptr, nullptr, dt_projb);
  // 7. chunked scan
  scan_p1<<<NB * NC * (DI / 256), 256, 0, stream>>>(dt_buf, u_buf, xdbl, A_log, Pbuf, Qbuf);
  scan_p2<<<NB * DS * (DI / 256), 256, 0, stream>>>(Pbuf, Qbuf);
  scan_p3<<<NB * NC * (DI / 256), 256, 0, stream>>>(dt_buf, u_buf, xdbl, A_log, Dp, z_buf, Qbuf);
  // 8. out_proj weights -> bf16, out_proj (MFMA) + fused residual -> d_out
  f2b_k<<<(DM * DI) / 256, 256, 0, stream>>>(out_projw, opw_bf, DM * DI);
  gemm_mfma<2><<<dim3(DM / TN, BL / TM), 256, 0, stream>>>(
      u_buf, opw_bf, BL, DM, DI, nullptr, nullptr, 0, out, x, nullptr);
}

// Round 9
// 618.710 us; speedup vs baseline: 1.1748x; 1.1748x over previous
//
#include <hip/hip_runtime.h>
#include <hip/hip_bf16.h>
#include <math.h>

#define DM 1024   // d_model
#define DI 2048   // d_inner
#define DS 16     // d_state
#define DC 4      // d_conv
#define DR 64     // dt_rank
#define NB 4      // batch
#define SL 2048   // seqlen
#define BL (NB * SL)        // 8192 rows
#define DXP (DR + 2 * DS)   // 96
#define NC 32               // scan chunks
#define CL (SL / NC)        // 64 steps per chunk

typedef __hip_bfloat16 bf16;
typedef __attribute__((ext_vector_type(8))) short short8;
typedef __attribute__((ext_vector_type(4))) float floatx4;
typedef unsigned int u32;

__device__ __forceinline__ float to_f(float v) { return v; }
__device__ __forceinline__ float to_f(bf16 v) { return __bfloat162float(v); }
template <typename T> __device__ __forceinline__ T from_f(float v);
template <> __device__ __forceinline__ float from_f<float>(float v) { return v; }
template <> __device__ __forceinline__ bf16 from_f<bf16>(float v) { return __float2bfloat16(v); }

__device__ __forceinline__ float bfbits2f(unsigned short u) {
  u32 b = ((u32)u) << 16;
  return __builtin_bit_cast(float, b);
}
__device__ __forceinline__ short f2bfbits(float v) {
  bf16 b = __float2bfloat16(v);
  return __builtin_bit_cast(short, b);
}
// fast silu: x * rcp(1+e^-x)  (v_rcp_f32, ~1 ulp — fine for bf16 outputs)
__device__ __forceinline__ float fsilu(float v) {
  return v * __builtin_amdgcn_rcpf(1.f + __expf(-v));
}

// ---------------- fp32 -> bf16 conversion ----------------
__global__ __launch_bounds__(256) void f2b_k(const float* __restrict__ src,
                                             bf16* __restrict__ dst, int n) {
  int i = blockIdx.x * 256 + threadIdx.x;
  if (i < n) dst[i] = from_f<bf16>(src[i]);
}

// ---------------- RMSNorm (bf16 out) ----------------
__global__ __launch_bounds__(256) void rmsnorm_k(const float* __restrict__ x,
                                                 const float* __restrict__ w,
                                                 bf16* __restrict__ o) {
  int row = blockIdx.x;
  const float* xr = x + (size_t)row * DM;
  float ss = 0.f;
  for (int i = threadIdx.x; i < DM; i += 256) { float v = xr[i]; ss += v * v; }
  for (int off = 32; off > 0; off >>= 1) ss += __shfl_down(ss, off);
  __shared__ float sred[4];
  __shared__ float sscale;
  if ((threadIdx.x & 63) == 0) sred[threadIdx.x >> 6] = ss;
  __syncthreads();
  if (threadIdx.x == 0) {
    float t = sred[0] + sred[1] + sred[2] + sred[3];
    sscale = rsqrtf(t / (float)DM + 1.1920929e-7f);
  }
  __syncthreads();
  float sc = sscale;
  bf16* orow = o + (size_t)row * DM;
  for (int i = threadIdx.x; i < DM; i += 256) orow[i] = from_f<bf16>(xr[i] * sc * w[i]);
}

// ======== MFMA bf16 GEMM: C[M,N] = A[M,K] @ W[N,K]^T, 128x128 tile ========
// (R6 explicit-staging form — measured 540 TF on in_proj; async variant regressed)
// MODE 1: in_proj  -> n<nsplit: raw bf16 to Cx ; n>=nsplit: silu -> Cz
// MODE 2: out_proj -> fp32 Cf = acc + R (residual)
// MODE 3: dt_proj  -> bf16 Cx = softplus(acc + bias[n])  [fast __logf form]
#define TM 128
#define TN 128
#define TK 32
#define LDK 40
template <int MODE>
__global__ __launch_bounds__(256) void gemm_mfma(const bf16* __restrict__ A,
                                                 const bf16* __restrict__ W,
                                                 int M, int N, int K,
                                                 bf16* __restrict__ Cx,
                                                 bf16* __restrict__ Cz, int nsplit,
                                                 float* __restrict__ Cf,
                                                 const float* __restrict__ R,
                                                 const float* __restrict__ bias) {
  __shared__ ushort Asm[TM][LDK];
  __shared__ ushort Bsm[TN][LDK];
  int bm = blockIdx.y * TM, bn = blockIdx.x * TN;
  int tid = threadIdx.x;
  int lane = tid & 63, wave = tid >> 6;
  int wm = (wave & 1) * 64, wn = (wave >> 1) * 64;
  int row15 = lane & 15, quad = lane >> 4;
  int srow = tid >> 1, skoff = (tid & 1) * 16;

  floatx4 acc[4][4] = {};

  const ushort* Au = (const ushort*)A;
  const ushort* Wu = (const ushort*)W;
  for (int k0 = 0; k0 < K; k0 += TK) {
    const ushort* ag = Au + (size_t)(bm + srow) * K + k0 + skoff;
    *(short8*)&Asm[srow][skoff]     = *(const short8*)ag;
    *(short8*)&Asm[srow][skoff + 8] = *(const short8*)(ag + 8);
    const ushort* wg = Wu + (size_t)(bn + srow) * K + k0 + skoff;
    *(short8*)&Bsm[srow][skoff]     = *(const short8*)wg;
    *(short8*)&Bsm[srow][skoff + 8] = *(const short8*)(wg + 8);
    __syncthreads();
    short8 a_f[4], b_f[4];
#pragma unroll
    for (int i = 0; i < 4; ++i)
      a_f[i] = *(const short8*)&Asm[wm + i * 16 + row15][quad * 8];
#pragma unroll
    for (int j = 0; j < 4; ++j)
      b_f[j] = *(const short8*)&Bsm[wn + j * 16 + row15][quad * 8];
#pragma unroll
    for (int i = 0; i < 4; ++i)
#pragma unroll
      for (int j = 0; j < 4; ++j)
        acc[i][j] = __builtin_amdgcn_mfma_f32_16x16x32_bf16(a_f[i], b_f[j], acc[i][j], 0, 0, 0);
    __syncthreads();
  }
#pragma unroll
  for (int mi = 0; mi < 4; ++mi) {
#pragma unroll
    for (int ni = 0; ni < 4; ++ni) {
#pragma unroll
      for (int reg = 0; reg < 4; ++reg) {
        int grow = bm + wm + mi * 16 + quad * 4 + reg;
        int gcol = bn + wn + ni * 16 + row15;
        float v = acc[mi][ni][reg];
        if (MODE == 1) {
          if (gcol < nsplit) {
            Cx[(size_t)grow * DI + gcol] = from_f<bf16>(v);
          } else {
            Cz[(size_t)grow * DI + (gcol - nsplit)] = from_f<bf16>(fsilu(v));
          }
        } else if (MODE == 2) {
          size_t o = (size_t)grow * N + gcol;
          Cf[o] = v + R[o];
        } else {  // MODE 3: dt softplus via HW exp/log (log1pf libm was ~100 us of VALU)
          float t = v + bias[gcol];
          float sp = (t > 20.f) ? t : __logf(1.f + __expf(t));
          Cx[(size_t)grow * N + gcol] = from_f<bf16>(sp);
        }
      }
    }
  }
}

// ======== x_proj split-K MFMA: xdbl[BL,96] += u[BL,2048-slice] @ xpw^T ========
#define XKS 128
__global__ __launch_bounds__(256) void xproj_k(const bf16* __restrict__ u,
                                               const bf16* __restrict__ w,
                                               float* __restrict__ xdbl) {
  __shared__ ushort Asm[128][LDK];
  __shared__ ushort Bsm[96][LDK];
  int kbase = blockIdx.x * XKS;
  int bm = blockIdx.y * 128;
  int tid = threadIdx.x;
  int lane = tid & 63, wave = tid >> 6;
  int row15 = lane & 15, quad = lane >> 4;
  int srow = tid >> 1, skoff = (tid & 1) * 16;

  floatx4 acc[2][6] = {};
  const ushort* Au = (const ushort*)u;
  const ushort* Wu = (const ushort*)w;
  for (int k0 = kbase; k0 < kbase + XKS; k0 += TK) {
    const ushort* ag = Au + (size_t)(bm + srow) * DI + k0 + skoff;
    *(short8*)&Asm[srow][skoff]     = *(const short8*)ag;
    *(short8*)&Asm[srow][skoff + 8] = *(const short8*)(ag + 8);
    if (tid < 192) {
      const ushort* wg = Wu + (size_t)srow * DI + k0 + skoff;
      *(short8*)&Bsm[srow][skoff]     = *(const short8*)wg;
      *(short8*)&Bsm[srow][skoff + 8] = *(const short8*)(wg + 8);
    }
    __syncthreads();
    short8 a_f[2], b_f[6];
#pragma unroll
    for (int i = 0; i < 2; ++i)
      a_f[i] = *(const short8*)&Asm[wave * 32 + i * 16 + row15][quad * 8];
#pragma unroll
    for (int j = 0; j < 6; ++j)
      b_f[j] = *(const short8*)&Bsm[j * 16 + row15][quad * 8];
#pragma unroll
    for (int i = 0; i < 2; ++i)
#pragma unroll
      for (int j = 0; j < 6; ++j)
        acc[i][j] = __builtin_amdgcn_mfma_f32_16x16x32_bf16(a_f[i], b_f[j], acc[i][j], 0, 0, 0);
    __syncthreads();
  }
#pragma unroll
  for (int mi = 0; mi < 2; ++mi)
#pragma unroll
    for (int nj = 0; nj < 6; ++nj)
#pragma unroll
      for (int reg = 0; reg < 4; ++reg) {
        int grow = bm + wave * 32 + mi * 16 + quad * 4 + reg;
        int gcol = nj * 16 + row15;
        atomicAdd(&xdbl[(size_t)grow * DXP + gcol], acc[mi][nj][reg]);
      }
}

// ---- extract xdbl[:, 0:64] -> bf16 [BL, 64] for the dt MFMA ----
__global__ __launch_bounds__(256) void dtex_k(const float* __restrict__ xdbl,
                                              bf16* __restrict__ dtin) {
  int i = blockIdx.x * 256 + threadIdx.x;  // BL*DR
  int r = i >> 6, c = i & 63;
  dtin[i] = from_f<bf16>(xdbl[(size_t)r * DXP + c]);
}

// ---------------- causal depthwise conv (K=4) + SiLU, 8-wide vectorized ----------------
__global__ __launch_bounds__(256) void conv_silu_k(const bf16* __restrict__ xin,
                                                   const float* __restrict__ cw,
                                                   const float* __restrict__ cb,
                                                   bf16* __restrict__ u) {
  int idx = blockIdx.x * 256 + threadIdx.x;    // BL * DI/8 threads
  int c0 = (idx & (DI / 8 - 1)) * 8;
  int bl = idx >> 8;                           // / (DI/8)
  int l = bl & (SL - 1);
  const ushort* base = (const ushort*)xin + (size_t)bl * DI + c0;
  float acc[8];
#pragma unroll
  for (int j = 0; j < 8; ++j) acc[j] = cb[c0 + j];
#pragma unroll
  for (int k = 0; k < DC; ++k) {
    int lk = l - (DC - 1) + k;
    if (lk >= 0) {
      short8 v = *(const short8*)(base + (ptrdiff_t)(k - (DC - 1)) * DI);
#pragma unroll
      for (int j = 0; j < 8; ++j)
        acc[j] += bfbits2f((unsigned short)v[j]) * cw[(c0 + j) * DC + k];
    }
  }
  short8 outv;
#pragma unroll
  for (int j = 0; j < 8; ++j) outv[j] = f2bfbits(fsilu(acc[j]));
  *(short8*)((ushort*)u + (size_t)bl * DI + c0) = outv;
}

// ======== chunked selective scan ========
__global__ __launch_bounds__(256) void scan_p1(const bf16* __restrict__ dts,
                                               const bf16* __restrict__ u,
                                               const float* __restrict__ xdbl,
                                               const float* __restrict__ A_log,
                                               float* __restrict__ Pbuf,
                                               float* __restrict__ Qbuf) {
  int bid = blockIdx.x;
  int b = bid >> 8;
  int c = (bid >> 3) & (NC - 1);
  int d = (bid & 7) * 256 + threadIdx.x;

  float A[DS], h[DS], P[DS];
#pragma unroll
  for (int s = 0; s < DS; ++s) {
    A[s] = -__expf(A_log[d * DS + s]);
    h[s] = 0.f; P[s] = 1.f;
  }
  size_t bl0 = (size_t)b * SL + c * CL;
  size_t base = bl0 * DI + d;
  size_t xb = bl0 * DXP + DR;
  for (int l = 0; l < CL; ++l) {
    float dtv = to_f(dts[base]);
    float uv = to_f(u[base]);
    float du = dtv * uv;
#pragma unroll
    for (int s = 0; s < DS; ++s) {
      float Bv = xdbl[xb + s];
      float dA = __expf(dtv * A[s]);
      h[s] = dA * h[s] + du * Bv;
      P[s] *= dA;
    }
    base += DI;
    xb += DXP;
  }
  size_t o = ((size_t)(b * NC + c) * DS) * DI + d;
#pragma unroll
  for (int s = 0; s < DS; ++s) {
    Pbuf[o + (size_t)s * DI] = P[s];
    Qbuf[o + (size_t)s * DI] = h[s];
  }
}

__global__ __launch_bounds__(256) void scan_p2(float* __restrict__ Pbuf,
                                               float* __restrict__ Qbuf) {
  int bid = blockIdx.x;
  int b = bid >> 7;
  int s = (bid >> 3) & (DS - 1);
  int d = (bid & 7) * 256 + threadIdx.x;
  float h = 0.f;
  for (int c = 0; c < NC; ++c) {
    size_t idx = ((size_t)((b * NC + c) * DS + s)) * DI + d;
    float Pv = Pbuf[idx];
    float qv = Qbuf[idx];
    Qbuf[idx] = h;
    h = Pv * h + qv;
  }
}

__global__ __launch_bounds__(256) void scan_p3(const bf16* __restrict__ dts,
                                               bf16* __restrict__ u,
                                               const float* __restrict__ xdbl,
                                               const float* __restrict__ A_log,
                                               const float* __restrict__ Dp,
                                               const bf16* __restrict__ g,
                                               const float* __restrict__ Qbuf) {
  int bid = blockIdx.x;
  int b = bid >> 8;
  int c = (bid >> 3) & (NC - 1);
  int d = (bid & 7) * 256 + threadIdx.x;

  float A[DS], h[DS];
  size_t o = ((size_t)(b * NC + c) * DS) * DI + d;
#pragma unroll
  for (int s = 0; s < DS; ++s) {
    A[s] = -__expf(A_log[d * DS + s]);
    h[s] = Qbuf[o + (size_t)s * DI];
  }
  float Dd = Dp[d];
  size_t bl0 = (size_t)b * SL + c * CL;
  size_t base = bl0 * DI + d;
  size_t xb = bl0 * DXP + DR;
  for (int l = 0; l < CL; ++l) {
    float dtv = to_f(dts[base]);
    float uv = to_f(u[base]);
    float gv = to_f(g[base]);
    float du = dtv * uv;
    float p0 = 0.f, p1 = 0.f, p2 = 0.f, p3 = 0.f;
#pragma unroll
    for (int s = 0; s < DS; s += 4) {
      float dA0 = __expf(dtv * A[s + 0]);
      float dA1 = __expf(dtv * A[s + 1]);
      float dA2 = __expf(dtv * A[s + 2]);
      float dA3 = __expf(dtv * A[s + 3]);
      h[s + 0] = dA0 * h[s + 0] + du * xdbl[xb + s + 0];
      h[s + 1] = dA1 * h[s + 1] + du * xdbl[xb + s + 1];
      h[s + 2] = dA2 * h[s + 2] + du * xdbl[xb + s + 2];
      h[s + 3] = dA3 * h[s + 3] + du * xdbl[xb + s + 3];
      p0 += h[s + 0] * xdbl[xb + DS + s + 0];
      p1 += h[s + 1] * xdbl[xb + DS + s + 1];
      p2 += h[s + 2] * xdbl[xb + DS + s + 2];
      p3 += h[s + 3] * xdbl[xb + DS + s + 3];
    }
    float yv = ((p0 + p1) + (p2 + p3)) + Dd * uv;
    u[base] = from_f<bf16>(yv * gv);
    base += DI;
    xb += DXP;
  }
}

extern "C" void kernel_launch(void* const* d_in, const int* in_sizes, int n_in,
                              void* d_out, int out_size, void* d_ws, size_t ws_size,
                              hipStream_t stream) {
  const float* x        = (const float*)d_in[0];
  const float* norm_w   = (const float*)d_in[1];
  const float* in_projw = (const float*)d_in[2];
  const float* conv_w   = (const float*)d_in[3];
  const float* conv_b   = (const float*)d_in[4];
  const float* x_projw  = (const float*)d_in[5];
  const float* dt_projw = (const float*)d_in[6];
  const float* dt_projb = (const float*)d_in[7];
  const float* A_log    = (const float*)d_in[8];
  const float* Dp       = (const float*)d_in[9];
  const float* out_projw= (const float*)d_in[10];
  float* out = (float*)d_out;

  // ---- workspace (~104 MiB), lifetime overlays ----
  char* wsb = (char*)d_ws;
  bf16* x_buf  = (bf16*)wsb;                           // x half; later dt; later opw_bf
  bf16* z_buf  = (bf16*)(wsb + (size_t)BL * DI * 2);   // silu(z) gate
  bf16* u_buf  = (bf16*)(wsb + (size_t)BL * DI * 4);   // xnorm_bf (early) then u/y
  char* ovl    = wsb + (size_t)BL * DI * 6;            // 8 MiB overlay
  bf16* ipw_bf = (bf16*)ovl;                           // phase A: in_proj w bf16 (8 MiB)
  // phase B overlay (after in_proj):
  float* xdbl   = (float*)ovl;                                 // 3 MiB
  bf16*  xpw_bf = (bf16*)(ovl + 3145728);                      // 0.375 MiB
  bf16*  dtw_bf = (bf16*)(ovl + 3538944);                      // 0.25 MiB
  bf16*  dtin_bf= (bf16*)(ovl + 3801088);                      // 1 MiB
  bf16* xnorm_bf = u_buf;
  bf16* dt_buf   = x_buf;   // x half dead after conv
  bf16* opw_bf   = x_buf;   // dt dead after scan p3
  float* Pbuf = out;        // d_out scratch until out_proj
  float* Qbuf = out + (size_t)NB * NC * DS * DI;

  // 1. in_proj weights -> bf16
  f2b_k<<<(2 * DI * DM) / 256, 256, 0, stream>>>(in_projw, ipw_bf, 2 * DI * DM);
  // 2. RMSNorm -> bf16
  rmsnorm_k<<<BL, 256, 0, stream>>>(x, norm_w, xnorm_bf);
  // 3. in_proj (MFMA): x half -> x_buf ; z half silu -> z_buf
  gemm_mfma<1><<<dim3(2 * DI / TN, BL / TM), 256, 0, stream>>>(
      xnorm_bf, ipw_bf, BL, 2 * DI, DM, x_buf, z_buf, DI, nullptr, nullptr, nullptr);
  // 4. causal conv + silu -> u_buf (8-wide)
  conv_silu_k<<<(BL * DI / 8) / 256, 256, 0, stream>>>(x_buf, conv_w, conv_b, u_buf);
  // 5. x_proj: zero xdbl, convert weights, split-K MFMA with atomic accumulate
  hipMemsetAsync(xdbl, 0, (size_t)BL * DXP * sizeof(float), stream);
  f2b_k<<<(DXP * DI + 255) / 256, 256, 0, stream>>>(x_projw, xpw_bf, DXP * DI);
  f2b_k<<<(DI * DR) / 256, 256, 0, stream>>>(dt_projw, dtw_bf, DI * DR);
  xproj_k<<<dim3(DI / XKS, BL / 128), 256, 0, stream>>>(u_buf, xpw_bf, xdbl);
  // 6. dt input slice -> bf16, dt_proj (MFMA, fused bias+softplus) -> dt_buf
  dtex_k<<<(BL * DR) / 256, 256, 0, stream>>>(xdbl, dtin_bf);
  gemm_mfma<3><<<dim3(DI / TN, BL / TM), 256, 0, stream>>>(
      dtin_bf, dtw_bf, BL, DI, DR, dt_buf, nullptr, 0, nullptr, nullptr, dt_projb);
  // 7. chunked scan
  scan_p1<<<NB * NC * (DI / 256), 256, 0, stream>>>(dt_buf, u_buf, xdbl, A_log, Pbuf, Qbuf);
  scan_p2<<<NB * DS * (DI / 256), 256, 0, stream>>>(Pbuf, Qbuf);
  scan_p3<<<NB * NC * (DI / 256), 256, 0, stream>>>(dt_buf, u_buf, xdbl, A_log, Dp, z_buf, Qbuf);
  // 8. out_proj weights -> bf16, out_proj (MFMA) + fused residual -> d_out
  f2b_k<<<(DM * DI) / 256, 256, 0, stream>>>(out_projw, opw_bf, DM * DI);
  gemm_mfma<2><<<dim3(DM / TN, BL / TM), 256, 0, stream>>>(
      u_buf, opw_bf, BL, DM, DI, nullptr, nullptr, 0, out, x, nullptr);
}